// Round 6
// baseline (244.718 us; speedup 1.0000x reference)
//
#include <hip/hip_runtime.h>

// MultiHeadAttention: x(4,2048,1024) @ W_attn(1024,3072)+b -> QKV -> causal MHA (16 heads, d=64)
// -> attn @ W_proj(1024,1024)+b. Inputs/outputs FLOAT32; internal compute bf16 MFMA + f32 accum.
//
//   0. convert x (f32) -> xb (bf16)
//   1. transpose+convert W_attn -> Wta (3072x1024 bf16), W_proj -> Wtp (1024x1024 bf16)
//   2. GEMM1: 256x256 8-phase counted-vmcnt pipeline (T2 swizzle + T5 setprio) -> Q*0.125,K,Vt
//   3. flash attention (causal, swapped-MFMA layout), 1 wave = 64 q rows -> Ab (B,T,C) bf16
//   4. GEMM2: 128x128 2-phase kernel, Ab @ Wtp^T + b_proj -> out (f32)

typedef __attribute__((ext_vector_type(8))) __bf16 bf16x8;
typedef __attribute__((ext_vector_type(4))) float f32x4;
typedef __attribute__((ext_vector_type(4))) short s16x4;

__device__ __forceinline__ unsigned short f2bf(float f) {
    unsigned u = __builtin_bit_cast(unsigned, f);
    u += 0x7fffu + ((u >> 16) & 1u);   // RNE
    return (unsigned short)(u >> 16);
}
__device__ __forceinline__ unsigned pack2bf(float a, float b) {
    return (unsigned)f2bf(a) | ((unsigned)f2bf(b) << 16);
}
// async 16B global -> LDS (HW: wave-uniform LDS base + lane*16; global addr per-lane)
__device__ __forceinline__ void gload16(const unsigned short* g, unsigned short* l) {
    __builtin_amdgcn_global_load_lds(
        (const __attribute__((address_space(1))) unsigned int*)g,
        (__attribute__((address_space(3))) unsigned int*)l, 16, 0, 0);
}

// ---------------- f32 -> bf16 elementwise convert (vectorized) ----------------
__global__ void convert_kernel(const float* __restrict__ in, unsigned short* __restrict__ out,
                               long n) {
    long i = ((long)blockIdx.x * blockDim.x + threadIdx.x) * 4;
    if (i >= n) return;
    f32x4 v = *reinterpret_cast<const f32x4*>(&in[i]);
    s16x4 o;
    o[0] = (short)f2bf(v[0]);
    o[1] = (short)f2bf(v[1]);
    o[2] = (short)f2bf(v[2]);
    o[3] = (short)f2bf(v[3]);
    *reinterpret_cast<s16x4*>(&out[i]) = o;
}

// ---------------- 32x32 tiled transpose+convert: Wt[n][k] = bf16(W[k][n]) ----------------
__global__ void transpose_kernel(const float* __restrict__ W,
                                 unsigned short* __restrict__ Wt,
                                 int K, int N) {
    __shared__ float t[32][33];
    const int tid = threadIdx.x;
    const int n0 = blockIdx.x * 32, k0 = blockIdx.y * 32;
    const int row = tid >> 3, c4 = (tid & 7) * 4;
    f32x4 v = *reinterpret_cast<const f32x4*>(&W[(size_t)(k0 + row) * N + n0 + c4]);
    t[row][c4 + 0] = v[0];
    t[row][c4 + 1] = v[1];
    t[row][c4 + 2] = v[2];
    t[row][c4 + 3] = v[3];
    __syncthreads();
    s16x4 o;
    o[0] = (short)f2bf(t[c4 + 0][row]);
    o[1] = (short)f2bf(t[c4 + 1][row]);
    o[2] = (short)f2bf(t[c4 + 2][row]);
    o[3] = (short)f2bf(t[c4 + 3][row]);
    *reinterpret_cast<s16x4*>(&Wt[(size_t)(n0 + row) * K + k0 + c4]) = o;
}

// ================== GEMM1: 256x256 tile, BK=64, 8 waves (2Mx4N), 8-phase pipeline ==================
// A (8192xK), Bt (3072xK) bf16 row-major. Epilogue scatters QKV.
// LDS: As/Bs[dbuf][ksub] = 256 rows x 32 k (16KB halves), st_16x32 swizzle (byte ^= ((byte>>9)&1)<<5)
// applied via pre-swizzled GLOBAL source (gload_lds writes linearly) + XOR'd ds_read address.
// Phase p of 8 per iter (2 K-tiles): {8x ds_read_b128, 1 half-tile stage, [vmcnt(2) @p4,p8],
// barrier, setprio(1), 16 MFMA, setprio(0), barrier}. Stage ledger: tile 2i+1 halves staged
// p8(prev),p1,p2,p3; tile 2i+2 @ p4..p7; tile 2i+3 A[k0] @ p8 — each region rewritten >=2 barriers
// after its last read; each half waited via the counted vmcnt before first read.
__global__ __launch_bounds__(512, 1)
void gemm256_kernel(const unsigned short* __restrict__ A,
                    const unsigned short* __restrict__ Bt,
                    const float* __restrict__ bias,
                    unsigned short* __restrict__ Qo,
                    unsigned short* __restrict__ Ko,
                    unsigned short* __restrict__ Vto,
                    int Kd) {
    __shared__ unsigned short As[2][2][256 * 32];
    __shared__ unsigned short Bs[2][2][256 * 32];
    const int tid = threadIdx.x;
    const int wave = tid >> 6, lane = tid & 63;
    const int l15 = lane & 15, lhi = lane >> 4;
    const int wm = wave >> 2, wn = wave & 3;
    const int sw = (l15 & 8) << 2;                 // st_16x32 read-side XOR (32B when row&8)
    // bijective XCD swizzle over 384 blocks (384 % 8 == 0), bn-fastest for A-panel reuse per XCD
    const int wg = (blockIdx.x & 7) * 48 + (blockIdx.x >> 3);
    const int bm = wg / 12, bn = wg % 12;
    const int m0 = bm * 256, n0 = bn * 256;

    f32x4 acc[8][4];
#pragma unroll
    for (int i = 0; i < 8; i++)
#pragma unroll
        for (int j = 0; j < 4; j++) acc[i][j] = f32x4{0.f, 0.f, 0.f, 0.f};

    // staging: per half-tile (256 rows x 32 k = 16KB) each thread issues 2 gload16.
    // linear LDS dest L = j*8192 + tid*16; source element = logical swz(L) (involution).
    const int L0 = tid * 16;
    const int Ls0 = L0 ^ (((L0 >> 9) & 1) << 5);
    const size_t ga0 = (size_t)(Ls0 >> 6) * Kd + ((Ls0 & 63) >> 1);
    const size_t ga1 = ga0 + (size_t)128 * Kd;
    const unsigned short* Ap = A + (size_t)m0 * Kd;
    const unsigned short* Bp = Bt + (size_t)n0 * Kd;

#define STAGEH(dst, src, kofs)                                                    \
    do {                                                                          \
        gload16((src) + ga0 + (kofs), (unsigned short*)((char*)(dst) + L0));      \
        gload16((src) + ga1 + (kofs), (unsigned short*)((char*)(dst) + 8192 + L0)); \
    } while (0)

#define VWAIT2 asm volatile("s_waitcnt vmcnt(2)" ::: "memory")

#define PHASE(db, ks, qm, STMT, WAITS)                                                     \
    do {                                                                                   \
        char* ab_ = (char*)&As[db][ks][0];                                                 \
        char* bb_ = (char*)&Bs[db][ks][0];                                                 \
        const int ar_ = (wm * 128 + (qm) * 64 + l15) * 64 + (lhi * 16 ^ sw);               \
        const int br_ = (wn * 64 + l15) * 64 + (lhi * 16 ^ sw);                            \
        bf16x8 av_[4], bv_[4];                                                             \
        _Pragma("unroll") for (int t_ = 0; t_ < 4; t_++) {                                 \
            av_[t_] = *(const bf16x8*)(ab_ + ar_ + t_ * 1024);                             \
            bv_[t_] = *(const bf16x8*)(bb_ + br_ + t_ * 1024);                             \
        }                                                                                  \
        STMT;                                                                              \
        WAITS;                                                                             \
        __builtin_amdgcn_s_barrier();                                                      \
        __builtin_amdgcn_s_setprio(1);                                                     \
        _Pragma("unroll") for (int t_ = 0; t_ < 4; t_++)                                   \
            _Pragma("unroll") for (int n_ = 0; n_ < 4; n_++)                               \
                acc[(qm) * 4 + t_][n_] = __builtin_amdgcn_mfma_f32_16x16x32_bf16(          \
                    av_[t_], bv_[n_], acc[(qm) * 4 + t_][n_], 0, 0, 0);                    \
        __builtin_amdgcn_s_setprio(0);                                                     \
        __builtin_amdgcn_s_barrier();                                                      \
    } while (0)

    // prologue: tile0 all 4 halves + tile1 A[k0]; vmcnt(2) -> tile0 landed, tile1-A may fly
    STAGEH(&As[0][0][0], Ap, 0);
    STAGEH(&Bs[0][0][0], Bp, 0);
    STAGEH(&As[0][1][0], Ap, 32);
    STAGEH(&Bs[0][1][0], Bp, 32);
    STAGEH(&As[1][0][0], Ap, 64);
    VWAIT2;
    __builtin_amdgcn_s_barrier();

    const int NITER = Kd >> 7;   // 2 K-tiles (BK=64) per iteration
    for (int i = 0; i < NITER; ++i) {
        const int kt1 = (2 * i + 1) * 64, kt2 = (2 * i + 2) * 64, kt3 = kt2 + 64;
        const bool sg = (i < NITER - 1);
        PHASE(0, 0, 0, { STAGEH(&Bs[1][0][0], Bp, kt1); }, );
        PHASE(0, 1, 0, { STAGEH(&As[1][1][0], Ap, kt1 + 32); }, );
        PHASE(0, 0, 1, { STAGEH(&Bs[1][1][0], Bp, kt1 + 32); }, );
        PHASE(0, 1, 1, { if (sg) STAGEH(&As[0][0][0], Ap, kt2); }, VWAIT2);
        PHASE(1, 0, 0, { if (sg) STAGEH(&Bs[0][0][0], Bp, kt2); }, );
        PHASE(1, 1, 0, { if (sg) STAGEH(&As[0][1][0], Ap, kt2 + 32); }, );
        PHASE(1, 0, 1, { if (sg) STAGEH(&Bs[0][1][0], Bp, kt2 + 32); }, );
        PHASE(1, 1, 1, { if (sg) STAGEH(&As[1][0][0], Ap, kt3); }, VWAIT2);
    }
#undef PHASE
#undef STAGEH
#undef VWAIT2

    // epilogue: QKV scatter. D[row = mf*16 + lhi*4 + r][col = nf*16 + l15] per wave 128x64 tile.
#pragma unroll
    for (int nf = 0; nf < 4; nf++) {
        const int col = n0 + wn * 64 + nf * 16 + l15;
        const float bv = bias[col];
        const int sel = col >> 10, c1 = col & 1023;
        const int h = c1 >> 6, d = c1 & 63;
#pragma unroll
        for (int mf = 0; mf < 8; mf++) {
            const int rbase = m0 + wm * 128 + mf * 16 + lhi * 4;
#pragma unroll
            for (int r = 0; r < 4; r++) {
                const int row = rbase + r;
                const float oval = acc[mf][nf][r] + bv;
                const int b = row >> 11, t = row & 2047;
                if (sel == 0)
                    Qo[(((size_t)(b * 16 + h)) * 2048 + t) * 64 + d] = f2bf(oval * 0.125f);
                else if (sel == 1)
                    Ko[(((size_t)(b * 16 + h)) * 2048 + t) * 64 + d] = f2bf(oval);
                else
                    Vto[(((size_t)(b * 16 + h)) * 64 + d) * 2048 + t] = f2bf(oval);
            }
        }
    }
}

// ------ GEMM2: 128x128 tile, BK=32, 2-phase double-buffered global_load_lds pipeline ------
__global__ __launch_bounds__(256, 2)
void gemm_kernel(const unsigned short* __restrict__ A,
                 const unsigned short* __restrict__ Bt,
                 const float* __restrict__ bias,
                 float* __restrict__ Cout,
                 int M, int N, int Kd) {
    __shared__ unsigned short As[2][128 * 32];
    __shared__ unsigned short Bs[2][128 * 32];
    const int tid = threadIdx.x;
    const int wave = tid >> 6, lane = tid & 63;
    const int l15 = lane & 15, lhi = lane >> 4;
    const int wm = wave >> 1, wn = wave & 1;
    const int m0 = blockIdx.x * 128, n0 = blockIdx.y * 128;

    f32x4 acc[4][4];
#pragma unroll
    for (int i = 0; i < 4; i++)
#pragma unroll
        for (int j = 0; j < 4; j++) acc[i][j] = f32x4{0.f, 0.f, 0.f, 0.f};

    const int r0 = tid >> 2, cb = (tid & 3) * 8;
    const unsigned short* Ap = &A[(size_t)(m0 + r0) * Kd + cb];
    const unsigned short* Bp = &Bt[(size_t)(n0 + r0) * Kd + cb];
    const size_t K64 = (size_t)64 * Kd;

#define STAGE(buf, k0)                                         \
    do {                                                       \
        gload16(Ap + (k0), &As[buf][tid * 8]);                 \
        gload16(Ap + K64 + (k0), &As[buf][64 * 32 + tid * 8]); \
        gload16(Bp + (k0), &Bs[buf][tid * 8]);                 \
        gload16(Bp + K64 + (k0), &Bs[buf][64 * 32 + tid * 8]); \
    } while (0)

#define COMPUTE(buf)                                                                         \
    do {                                                                                     \
        bf16x8 af[4], bfr[4];                                                                \
        _Pragma("unroll") for (int i = 0; i < 4; i++) {                                      \
            af[i]  = *reinterpret_cast<const bf16x8*>(&As[buf][(wm * 64 + i * 16 + l15) * 32 + lhi * 8]); \
            bfr[i] = *reinterpret_cast<const bf16x8*>(&Bs[buf][(wn * 64 + i * 16 + l15) * 32 + lhi * 8]); \
        }                                                                                    \
        _Pragma("unroll") for (int i = 0; i < 4; i++)                                        \
            _Pragma("unroll") for (int j = 0; j < 4; j++)                                    \
                acc[i][j] = __builtin_amdgcn_mfma_f32_16x16x32_bf16(af[i], bfr[j], acc[i][j], 0, 0, 0); \
    } while (0)

    STAGE(0, 0);
    __syncthreads();
    for (int k0 = 0; k0 < Kd; k0 += 64) {
        STAGE(1, k0 + 32);
        COMPUTE(0);
        __syncthreads();
        if (k0 + 64 < Kd) STAGE(0, k0 + 64);
        COMPUTE(1);
        __syncthreads();
    }
#undef STAGE
#undef COMPUTE

#pragma unroll
    for (int j = 0; j < 4; j++) {
        const int col = n0 + wn * 64 + j * 16 + l15;
        const float bv = bias[col];
#pragma unroll
        for (int i = 0; i < 4; i++) {
            const int rbase = m0 + wm * 64 + i * 16 + lhi * 4;
#pragma unroll
            for (int r = 0; r < 4; r++)
                Cout[(size_t)(rbase + r) * N + col] = acc[i][j][r] + bv;
        }
    }
}

// ---------------- causal flash attention, swapped-MFMA layout ----------------
__global__ __launch_bounds__(256, 2)
void attn_kernel(const unsigned short* __restrict__ Q,
                 const unsigned short* __restrict__ Kg,
                 const unsigned short* __restrict__ Vt,
                 unsigned short* __restrict__ Aout) {
    __shared__ unsigned int Pl[4][16 * 36];     // per-wave P^T tile: [q=16][k=64] bf16, 144B rows
    const int tid = threadIdx.x, wave = tid >> 6, lane = tid & 63;
    const int l15 = lane & 15, lhi = lane >> 4;
    const int bid = blockIdx.x;
    const int head = bid & 63;
    const int j = bid >> 6;
    const int qb = (j < 4) ? j : (11 - j);       // complement pairing: qb(j)+qb(j+4)=7
    const int q0w = qb * 256 + wave * 64;
    const unsigned short* Qh = Q + (size_t)head * (2048 * 64);
    const unsigned short* Kh = Kg + (size_t)head * (2048 * 64);
    const unsigned short* Vh = Vt + (size_t)head * (64 * 2048);
    unsigned int* P = &Pl[wave][0];

    bf16x8 qfr[4][2];
#pragma unroll
    for (int qf = 0; qf < 4; qf++)
#pragma unroll
        for (int dh = 0; dh < 2; dh++)
            qfr[qf][dh] = *reinterpret_cast<const bf16x8*>(
                &Qh[(size_t)(q0w + qf * 16 + l15) * 64 + dh * 32 + lhi * 8]);

    f32x4 o[4][4];   // [df][qf], O^T[d=df*16+lhi*4+r][q=qf*16+l15]
#pragma unroll
    for (int df = 0; df < 4; df++)
#pragma unroll
        for (int qf = 0; qf < 4; qf++) o[df][qf] = f32x4{0.f, 0.f, 0.f, 0.f};
    float m[4] = {-1e30f, -1e30f, -1e30f, -1e30f};
    float l[4] = {0.f, 0.f, 0.f, 0.f};

    const int ntiles = (q0w >> 6) + 1;
    for (int t = 0; t < ntiles; ++t) {
        const int kt = t * 64;
        const bool masked = (t == ntiles - 1);
        bf16x8 kfr[4][2], vfr[4][2];
#pragma unroll
        for (int kf = 0; kf < 4; kf++)
#pragma unroll
            for (int dh = 0; dh < 2; dh++)
                kfr[kf][dh] = *reinterpret_cast<const bf16x8*>(
                    &Kh[(size_t)(kt + kf * 16 + l15) * 64 + dh * 32 + lhi * 8]);
#pragma unroll
        for (int df = 0; df < 4; df++)
#pragma unroll
            for (int kc = 0; kc < 2; kc++)
                vfr[df][kc] = *reinterpret_cast<const bf16x8*>(
                    &Vh[(size_t)(df * 16 + l15) * 2048 + kt + kc * 32 + lhi * 8]);

#pragma unroll
        for (int qf = 0; qf < 4; qf++) {
            f32x4 s[4];
#pragma unroll
            for (int kf = 0; kf < 4; kf++) {
                s[kf] = __builtin_amdgcn_mfma_f32_16x16x32_bf16(kfr[kf][0], qfr[qf][0],
                                                                f32x4{0.f, 0.f, 0.f, 0.f}, 0, 0, 0);
                s[kf] = __builtin_amdgcn_mfma_f32_16x16x32_bf16(kfr[kf][1], qfr[qf][1], s[kf], 0, 0, 0);
            }
            if (masked) {
#pragma unroll
                for (int kf = 0; kf < 4; kf++)
#pragma unroll
                    for (int r = 0; r < 4; r++)
                        if (kf * 16 + lhi * 4 + r > qf * 16 + l15) s[kf][r] = -1e30f;
            }
            float tm = s[0][0];
#pragma unroll
            for (int kf = 0; kf < 4; kf++)
#pragma unroll
                for (int r = 0; r < 4; r++) tm = fmaxf(tm, s[kf][r]);
            tm = fmaxf(tm, __shfl_xor(tm, 16));
            tm = fmaxf(tm, __shfl_xor(tm, 32));
            const float mn = fmaxf(m[qf], tm);
            const float corr = __expf(m[qf] - mn);
            m[qf] = mn;
            float rs = 0.f;
#pragma unroll
            for (int kf = 0; kf < 4; kf++)
#pragma unroll
                for (int r = 0; r < 4; r++) {
                    const float p = __expf(s[kf][r] - mn);
                    s[kf][r] = p;
                    rs += p;
                }
            rs += __shfl_xor(rs, 16);
            rs += __shfl_xor(rs, 32);
            l[qf] = l[qf] * corr + rs;
#pragma unroll
            for (int df = 0; df < 4; df++)
#pragma unroll
                for (int r = 0; r < 4; r++) o[df][qf][r] *= corr;

#pragma unroll
            for (int kf = 0; kf < 4; kf++) {
                P[l15 * 36 + kf * 8 + lhi * 2 + 0] = pack2bf(s[kf][0], s[kf][1]);
                P[l15 * 36 + kf * 8 + lhi * 2 + 1] = pack2bf(s[kf][2], s[kf][3]);
            }
            asm volatile("s_waitcnt lgkmcnt(0)" ::: "memory");
            bf16x8 pb0 = *reinterpret_cast<const bf16x8*>(&P[l15 * 36 + 0 * 16 + lhi * 4]);
            bf16x8 pb1 = *reinterpret_cast<const bf16x8*>(&P[l15 * 36 + 1 * 16 + lhi * 4]);
#pragma unroll
            for (int df = 0; df < 4; df++) {
                o[df][qf] = __builtin_amdgcn_mfma_f32_16x16x32_bf16(vfr[df][0], pb0, o[df][qf], 0, 0, 0);
                o[df][qf] = __builtin_amdgcn_mfma_f32_16x16x32_bf16(vfr[df][1], pb1, o[df][qf], 0, 0, 0);
            }
        }
    }

    const int b = head >> 4, h = head & 15;
#pragma unroll
    for (int qf = 0; qf < 4; qf++) {
        const float inv = 1.0f / l[qf];
        unsigned short* op = Aout + ((size_t)(b * 2048 + q0w + qf * 16 + l15)) * 1024 + h * 64;
#pragma unroll
        for (int df = 0; df < 4; df++) {
            *reinterpret_cast<unsigned*>(&op[df * 16 + lhi * 4]) =
                pack2bf(o[df][qf][0] * inv, o[df][qf][1] * inv);
            *reinterpret_cast<unsigned*>(&op[df * 16 + lhi * 4 + 2]) =
                pack2bf(o[df][qf][2] * inv, o[df][qf][3] * inv);
        }
    }
}

extern "C" void kernel_launch(void* const* d_in, const int* in_sizes, int n_in,
                              void* d_out, int out_size, void* d_ws, size_t ws_size,
                              hipStream_t stream) {
    const float* x     = (const float*)d_in[0];
    const float* Wattn = (const float*)d_in[1];
    const float* battn = (const float*)d_in[2];
    const float* Wproj = (const float*)d_in[3];
    const float* bproj = (const float*)d_in[4];
    float* out = (float*)d_out;

    unsigned short* ws = (unsigned short*)d_ws;
    const size_t HS = (size_t)4 * 16 * 2048 * 64;
    unsigned short* Qb  = ws;
    unsigned short* Kb  = Qb + HS;
    unsigned short* Vtb = Kb + HS;
    unsigned short* Ab  = Vtb + HS;
    unsigned short* Wta = Ab + HS;
    unsigned short* Wtp = Wta + (size_t)3072 * 1024;
    unsigned short* xb  = Wtp + (size_t)1024 * 1024;

    convert_kernel<<<8192, 256, 0, stream>>>(x, xb, (long)HS);
    transpose_kernel<<<dim3(96, 32), 256, 0, stream>>>(Wattn, Wta, 1024, 3072);
    transpose_kernel<<<dim3(32, 32), 256, 0, stream>>>(Wproj, Wtp, 1024, 1024);
    gemm256_kernel<<<384, 512, 0, stream>>>(xb, Wta, battn, Qb, Kb, Vtb, 1024);
    attn_kernel<<<512, 256, 0, stream>>>(Qb, Kb, Vtb, Ab);
    gemm_kernel<<<dim3(64, 8), 256, 0, stream>>>(Ab, Wtp, bproj, out, 8192, 1024, 1024);
}

// Round 7
// 197.895 us; speedup vs baseline: 1.2366x; 1.2366x over previous
//
#include <hip/hip_runtime.h>

// MultiHeadAttention: x(4,2048,1024) @ W_attn(1024,3072)+b -> QKV -> causal MHA (16 heads, d=64)
// -> attn @ W_proj(1024,1024)+b. Inputs/outputs FLOAT32; internal compute bf16 MFMA + f32 accum.
//
//   0. convert x (f32) -> xb (bf16)
//   1. transpose+convert W_attn -> Wta (3072x1024 bf16), W_proj -> Wtp (1024x1024 bf16)
//   2. GEMM1: 128x128 tile, BK=64 single-buffer gload_lds, conflict-free XOR swizzle -> Q*0.125,K,Vt
//   3. flash attention (causal, swapped-MFMA layout), 1 wave = 64 q rows -> Ab (B,T,C) bf16
//   4. GEMM2: same structure, Ab @ Wtp^T + b_proj -> out (f32)

typedef __attribute__((ext_vector_type(8))) __bf16 bf16x8;
typedef __attribute__((ext_vector_type(4))) float f32x4;
typedef __attribute__((ext_vector_type(4))) short s16x4;

__device__ __forceinline__ unsigned short f2bf(float f) {
    unsigned u = __builtin_bit_cast(unsigned, f);
    u += 0x7fffu + ((u >> 16) & 1u);   // RNE
    return (unsigned short)(u >> 16);
}
__device__ __forceinline__ unsigned pack2bf(float a, float b) {
    return (unsigned)f2bf(a) | ((unsigned)f2bf(b) << 16);
}
// async 16B global -> LDS (HW: wave-uniform LDS base + lane*16; global addr per-lane)
__device__ __forceinline__ void gload16(const unsigned short* g, unsigned short* l) {
    __builtin_amdgcn_global_load_lds(
        (const __attribute__((address_space(1))) unsigned int*)g,
        (__attribute__((address_space(3))) unsigned int*)l, 16, 0, 0);
}

// ---------------- f32 -> bf16 elementwise convert (vectorized) ----------------
__global__ void convert_kernel(const float* __restrict__ in, unsigned short* __restrict__ out,
                               long n) {
    long i = ((long)blockIdx.x * blockDim.x + threadIdx.x) * 4;
    if (i >= n) return;
    f32x4 v = *reinterpret_cast<const f32x4*>(&in[i]);
    s16x4 o;
    o[0] = (short)f2bf(v[0]);
    o[1] = (short)f2bf(v[1]);
    o[2] = (short)f2bf(v[2]);
    o[3] = (short)f2bf(v[3]);
    *reinterpret_cast<s16x4*>(&out[i]) = o;
}

// ---------------- 32x32 tiled transpose+convert: Wt[n][k] = bf16(W[k][n]) ----------------
__global__ void transpose_kernel(const float* __restrict__ W,
                                 unsigned short* __restrict__ Wt,
                                 int K, int N) {
    __shared__ float t[32][33];
    const int tid = threadIdx.x;
    const int n0 = blockIdx.x * 32, k0 = blockIdx.y * 32;
    const int row = tid >> 3, c4 = (tid & 7) * 4;
    f32x4 v = *reinterpret_cast<const f32x4*>(&W[(size_t)(k0 + row) * N + n0 + c4]);
    t[row][c4 + 0] = v[0];
    t[row][c4 + 1] = v[1];
    t[row][c4 + 2] = v[2];
    t[row][c4 + 3] = v[3];
    __syncthreads();
    s16x4 o;
    o[0] = (short)f2bf(t[c4 + 0][row]);
    o[1] = (short)f2bf(t[c4 + 1][row]);
    o[2] = (short)f2bf(t[c4 + 2][row]);
    o[3] = (short)f2bf(t[c4 + 3][row]);
    *reinterpret_cast<s16x4*>(&Wt[(size_t)(n0 + row) * K + k0 + c4]) = o;
}

// ====== 128x128 tile MFMA GEMM, BK=64 single-buffer gload_lds, XOR-swizzled LDS ======
// LDS layout [128 rows][64 k] linear (row stride 128B). Swizzle: stored(row, c) =
// logical(row, c ^ ((row&7)<<4)) [bytes], applied on the GLOBAL source (gload_lds writes
// linearly) and inverted on the ds_read address — conflict-free b128 reads (2 lanes/bank).
// Per K-step: 8 gload16 -> barrier(drain) -> 16 ds_read_b128 + 32 MFMA -> barrier.
// MODE 0: C = A @ Bt^T + bias -> Cout (f32). MODE 1: scatter QKV bf16 (Q pre-scaled 0.125).
template <int MODE>
__global__ __launch_bounds__(256, 2)
void gemm_kernel(const unsigned short* __restrict__ A,
                 const unsigned short* __restrict__ Bt,
                 const float* __restrict__ bias,
                 float* __restrict__ Cout,
                 unsigned short* __restrict__ Qo,
                 unsigned short* __restrict__ Ko,
                 unsigned short* __restrict__ Vto,
                 int M, int N, int Kd) {
    __shared__ unsigned short As[128 * 64];
    __shared__ unsigned short Bs[128 * 64];
    const int tid = threadIdx.x;
    const int wave = tid >> 6, lane = tid & 63;
    const int l15 = lane & 15, lhi = lane >> 4;
    const int wm = wave >> 1, wn = wave & 1;
    const int m0 = blockIdx.x * 128, n0 = blockIdx.y * 128;

    f32x4 acc[4][4];
#pragma unroll
    for (int i = 0; i < 4; i++)
#pragma unroll
        for (int j = 0; j < 4; j++) acc[i][j] = f32x4{0.f, 0.f, 0.f, 0.f};

    // staging: thread -> (row = tid>>3 in 4 blocks of 32 rows, 16B chunk (tid&7) of the row)
    // source col pre-swizzled: cswz = ((tid&7) ^ (row&7)) * 8 elems
    const int r0 = tid >> 3;
    const int cswz = (((tid & 7) ^ (r0 & 7)) << 3);
    const unsigned short* Ap = &A[(size_t)(m0 + r0) * Kd + cswz];
    const unsigned short* Bp = &Bt[(size_t)(n0 + r0) * Kd + cswz];
    const size_t K32 = (size_t)32 * Kd;
    // ds_read col offset (elems): (ks*32 + lhi*8) ^ ((l15&7)<<3)
    const int csw0 = (lhi * 8) ^ ((l15 & 7) << 3);

    for (int k0 = 0; k0 < Kd; k0 += 64) {
#pragma unroll
        for (int blk = 0; blk < 4; blk++) {
            gload16(Ap + blk * K32 + k0, &As[blk * 2048 + tid * 8]);
            gload16(Bp + blk * K32 + k0, &Bs[blk * 2048 + tid * 8]);
        }
        __syncthreads();   // drains vmcnt(0): buffer ready

        bf16x8 av[2][4], bv[2][4];
#pragma unroll
        for (int ks = 0; ks < 2; ks++)
#pragma unroll
            for (int i = 0; i < 4; i++) {
                av[ks][i] = *reinterpret_cast<const bf16x8*>(
                    &As[(wm * 64 + i * 16 + l15) * 64 + (ks * 32 ^ csw0)]);
                bv[ks][i] = *reinterpret_cast<const bf16x8*>(
                    &Bs[(wn * 64 + i * 16 + l15) * 64 + (ks * 32 ^ csw0)]);
            }
#pragma unroll
        for (int ks = 0; ks < 2; ks++)
#pragma unroll
            for (int i = 0; i < 4; i++)
#pragma unroll
                for (int j = 0; j < 4; j++)
                    acc[i][j] = __builtin_amdgcn_mfma_f32_16x16x32_bf16(av[ks][i], bv[ks][j],
                                                                        acc[i][j], 0, 0, 0);
        __syncthreads();
    }

    // epilogue: D[row=(lane>>4)*4+r][col=lane&15] per 16x16 fragment
#pragma unroll
    for (int j = 0; j < 4; j++) {
        const int col = n0 + wn * 64 + j * 16 + l15;
        const float bv = bias[col];
#pragma unroll
        for (int i = 0; i < 4; i++) {
            const int rbase = m0 + wm * 64 + i * 16 + lhi * 4;
#pragma unroll
            for (int r = 0; r < 4; r++) {
                const int row = rbase + r;
                const float oval = acc[i][j][r] + bv;
                if (MODE == 0) {
                    Cout[(size_t)row * N + col] = oval;
                } else {
                    const int sel = col >> 10, c1 = col & 1023;
                    const int h = c1 >> 6, d = c1 & 63;
                    const int b = row >> 11, t = row & 2047;
                    if (sel == 0)
                        Qo[(((size_t)(b * 16 + h)) * 2048 + t) * 64 + d] = f2bf(oval * 0.125f);
                    else if (sel == 1)
                        Ko[(((size_t)(b * 16 + h)) * 2048 + t) * 64 + d] = f2bf(oval);
                    else
                        Vto[(((size_t)(b * 16 + h)) * 64 + d) * 2048 + t] = f2bf(oval);
                }
            }
        }
    }
}

// ---------------- causal flash attention, swapped-MFMA layout ----------------
// 1 wave = 64 q rows (4 q-frags); block = 4 waves = 256 q rows; grid = 512 (head = bid&63).
__global__ __launch_bounds__(256, 2)
void attn_kernel(const unsigned short* __restrict__ Q,
                 const unsigned short* __restrict__ Kg,
                 const unsigned short* __restrict__ Vt,
                 unsigned short* __restrict__ Aout) {
    __shared__ unsigned int Pl[4][16 * 36];     // per-wave P^T tile: [q=16][k=64] bf16, 144B rows
    const int tid = threadIdx.x, wave = tid >> 6, lane = tid & 63;
    const int l15 = lane & 15, lhi = lane >> 4;
    const int bid = blockIdx.x;
    const int head = bid & 63;
    const int j = bid >> 6;
    const int qb = (j < 4) ? j : (11 - j);       // complement pairing: qb(j)+qb(j+4)=7
    const int q0w = qb * 256 + wave * 64;
    const unsigned short* Qh = Q + (size_t)head * (2048 * 64);
    const unsigned short* Kh = Kg + (size_t)head * (2048 * 64);
    const unsigned short* Vh = Vt + (size_t)head * (64 * 2048);
    unsigned int* P = &Pl[wave][0];

    bf16x8 qfr[4][2];
#pragma unroll
    for (int qf = 0; qf < 4; qf++)
#pragma unroll
        for (int dh = 0; dh < 2; dh++)
            qfr[qf][dh] = *reinterpret_cast<const bf16x8*>(
                &Qh[(size_t)(q0w + qf * 16 + l15) * 64 + dh * 32 + lhi * 8]);

    f32x4 o[4][4];   // [df][qf], O^T[d=df*16+lhi*4+r][q=qf*16+l15]
#pragma unroll
    for (int df = 0; df < 4; df++)
#pragma unroll
        for (int qf = 0; qf < 4; qf++) o[df][qf] = f32x4{0.f, 0.f, 0.f, 0.f};
    float m[4] = {-1e30f, -1e30f, -1e30f, -1e30f};
    float l[4] = {0.f, 0.f, 0.f, 0.f};

    const int ntiles = (q0w >> 6) + 1;
    for (int t = 0; t < ntiles; ++t) {
        const int kt = t * 64;
        const bool masked = (t == ntiles - 1);
        bf16x8 kfr[4][2], vfr[4][2];
#pragma unroll
        for (int kf = 0; kf < 4; kf++)
#pragma unroll
            for (int dh = 0; dh < 2; dh++)
                kfr[kf][dh] = *reinterpret_cast<const bf16x8*>(
                    &Kh[(size_t)(kt + kf * 16 + l15) * 64 + dh * 32 + lhi * 8]);
#pragma unroll
        for (int df = 0; df < 4; df++)
#pragma unroll
            for (int kc = 0; kc < 2; kc++)
                vfr[df][kc] = *reinterpret_cast<const bf16x8*>(
                    &Vh[(size_t)(df * 16 + l15) * 2048 + kt + kc * 32 + lhi * 8]);

#pragma unroll
        for (int qf = 0; qf < 4; qf++) {
            f32x4 s[4];
#pragma unroll
            for (int kf = 0; kf < 4; kf++) {
                s[kf] = __builtin_amdgcn_mfma_f32_16x16x32_bf16(kfr[kf][0], qfr[qf][0],
                                                                f32x4{0.f, 0.f, 0.f, 0.f}, 0, 0, 0);
                s[kf] = __builtin_amdgcn_mfma_f32_16x16x32_bf16(kfr[kf][1], qfr[qf][1], s[kf], 0, 0, 0);
            }
            if (masked) {
#pragma unroll
                for (int kf = 0; kf < 4; kf++)
#pragma unroll
                    for (int r = 0; r < 4; r++)
                        if (kf * 16 + lhi * 4 + r > qf * 16 + l15) s[kf][r] = -1e30f;
            }
            float tm = s[0][0];
#pragma unroll
            for (int kf = 0; kf < 4; kf++)
#pragma unroll
                for (int r = 0; r < 4; r++) tm = fmaxf(tm, s[kf][r]);
            tm = fmaxf(tm, __shfl_xor(tm, 16));
            tm = fmaxf(tm, __shfl_xor(tm, 32));
            const float mn = fmaxf(m[qf], tm);
            const float corr = __expf(m[qf] - mn);
            m[qf] = mn;
            float rs = 0.f;
#pragma unroll
            for (int kf = 0; kf < 4; kf++)
#pragma unroll
                for (int r = 0; r < 4; r++) {
                    const float p = __expf(s[kf][r] - mn);
                    s[kf][r] = p;
                    rs += p;
                }
            rs += __shfl_xor(rs, 16);
            rs += __shfl_xor(rs, 32);
            l[qf] = l[qf] * corr + rs;
#pragma unroll
            for (int df = 0; df < 4; df++)
#pragma unroll
                for (int r = 0; r < 4; r++) o[df][qf][r] *= corr;

#pragma unroll
            for (int kf = 0; kf < 4; kf++) {
                P[l15 * 36 + kf * 8 + lhi * 2 + 0] = pack2bf(s[kf][0], s[kf][1]);
                P[l15 * 36 + kf * 8 + lhi * 2 + 1] = pack2bf(s[kf][2], s[kf][3]);
            }
            asm volatile("s_waitcnt lgkmcnt(0)" ::: "memory");
            bf16x8 pb0 = *reinterpret_cast<const bf16x8*>(&P[l15 * 36 + 0 * 16 + lhi * 4]);
            bf16x8 pb1 = *reinterpret_cast<const bf16x8*>(&P[l15 * 36 + 1 * 16 + lhi * 4]);
#pragma unroll
            for (int df = 0; df < 4; df++) {
                o[df][qf] = __builtin_amdgcn_mfma_f32_16x16x32_bf16(vfr[df][0], pb0, o[df][qf], 0, 0, 0);
                o[df][qf] = __builtin_amdgcn_mfma_f32_16x16x32_bf16(vfr[df][1], pb1, o[df][qf], 0, 0, 0);
            }
        }
    }

    const int b = head >> 4, h = head & 15;
#pragma unroll
    for (int qf = 0; qf < 4; qf++) {
        const float inv = 1.0f / l[qf];
        unsigned short* op = Aout + ((size_t)(b * 2048 + q0w + qf * 16 + l15)) * 1024 + h * 64;
#pragma unroll
        for (int df = 0; df < 4; df++) {
            *reinterpret_cast<unsigned*>(&op[df * 16 + lhi * 4]) =
                pack2bf(o[df][qf][0] * inv, o[df][qf][1] * inv);
            *reinterpret_cast<unsigned*>(&op[df * 16 + lhi * 4 + 2]) =
                pack2bf(o[df][qf][2] * inv, o[df][qf][3] * inv);
        }
    }
}

extern "C" void kernel_launch(void* const* d_in, const int* in_sizes, int n_in,
                              void* d_out, int out_size, void* d_ws, size_t ws_size,
                              hipStream_t stream) {
    const float* x     = (const float*)d_in[0];
    const float* Wattn = (const float*)d_in[1];
    const float* battn = (const float*)d_in[2];
    const float* Wproj = (const float*)d_in[3];
    const float* bproj = (const float*)d_in[4];
    float* out = (float*)d_out;

    unsigned short* ws = (unsigned short*)d_ws;
    const size_t HS = (size_t)4 * 16 * 2048 * 64;
    unsigned short* Qb  = ws;
    unsigned short* Kb  = Qb + HS;
    unsigned short* Vtb = Kb + HS;
    unsigned short* Ab  = Vtb + HS;
    unsigned short* Wta = Ab + HS;
    unsigned short* Wtp = Wta + (size_t)3072 * 1024;
    unsigned short* xb  = Wtp + (size_t)1024 * 1024;

    convert_kernel<<<8192, 256, 0, stream>>>(x, xb, (long)HS);
    transpose_kernel<<<dim3(96, 32), 256, 0, stream>>>(Wattn, Wta, 1024, 3072);
    transpose_kernel<<<dim3(32, 32), 256, 0, stream>>>(Wproj, Wtp, 1024, 1024);
    gemm_kernel<1><<<dim3(64, 24), 256, 0, stream>>>(xb, Wta, battn, nullptr, Qb, Kb, Vtb,
                                                     8192, 3072, 1024);
    attn_kernel<<<512, 256, 0, stream>>>(Qb, Kb, Vtb, Ab);
    gemm_kernel<0><<<dim3(64, 8), 256, 0, stream>>>(Ab, Wtp, bproj, out, nullptr, nullptr, nullptr,
                                                    8192, 1024, 1024);
}